// Round 5
// baseline (189.647 us; speedup 1.0000x reference)
//
#include <hip/hip_runtime.h>
#include <stdint.h>

#define Bn 256
#define Tn 50
#define Mn 20
#define En 128
#define G3 384
#define MT 64
#define LDA 132

__device__ __forceinline__ float sigmoidf(float x) {
    return 1.0f / (1.0f + __expf(-x));
}
__device__ __forceinline__ float tanh_safe(float a) {
    float ax = fabsf(a);
    float e2 = __expf(-2.0f * ax);
    return copysignf((1.0f - e2) / (1.0f + e2), a);
}

// ---------------------------------------------------------------------------
// Kernel 1: basket-mean gather -> ub [B*T][128]  (stored in d_out region)
// ---------------------------------------------------------------------------
__global__ __launch_bounds__(256) void gather_kernel(
    const int*   __restrict__ item_ids,
    const int*   __restrict__ basket_sizes,
    const float* __restrict__ emb,
    float* __restrict__ ub)
{
    const int bt   = blockIdx.x * 8 + (threadIdx.x >> 5);
    const int lane = threadIdx.x & 31;
    const int* ids = item_ids + (size_t)bt * Mn;
    float ax = 0.f, ay = 0.f, az = 0.f, aw = 0.f;
    #pragma unroll
    for (int m = 0; m < Mn; ++m) {
        const float4 v = *(const float4*)(emb + (size_t)ids[m] * En + lane * 4);
        ax += v.x; ay += v.y; az += v.z; aw += v.w;
    }
    const float inv = 1.0f / (float)basket_sizes[bt];
    *(float4*)(ub + (size_t)bt * En + lane * 4) =
        make_float4(ax * inv, ay * inv, az * inv, aw * inv);
}

// ---------------------------------------------------------------------------
// Kernel 2: xg = ub @ W_ih^T + b_ih.
// grid = 1200 blocks: 200 M-tiles x 6 N-chunks of 64; 256 threads; 4x4 tile.
// ---------------------------------------------------------------------------
__global__ __launch_bounds__(256, 2) void gemm_kernel(
    const float* __restrict__ ub,
    const float* __restrict__ W_ih,
    const float* __restrict__ b_ih,
    float* __restrict__ xg)
{
    __shared__ float A[MT][LDA];
    __shared__ float Bt[64][LDA];

    const int tid  = threadIdx.x;
    const int mt   = blockIdx.x / 6;
    const int nc   = blockIdx.x % 6;
    const int row0 = mt * MT;
    const int col0 = nc * 64;

    {
        const int r = tid >> 2, seg = tid & 3;
        const float4* srcA = (const float4*)(ub + (size_t)(row0 + r) * En + seg * 32);
        const float4* srcB = (const float4*)(W_ih + (size_t)(col0 + r) * En + seg * 32);
        float4* dstA = (float4*)&A[r][seg * 32];
        float4* dstB = (float4*)&Bt[r][seg * 32];
        #pragma unroll
        for (int c = 0; c < 8; ++c) { dstA[c] = srcA[c]; dstB[c] = srcB[c]; }
    }
    __syncthreads();

    const int tx = tid & 15;
    const int ty = tid >> 4;

    float acc[4][4];
    #pragma unroll
    for (int i = 0; i < 4; ++i)
        #pragma unroll
        for (int u = 0; u < 4; ++u) acc[i][u] = 0.0f;

    #pragma unroll 4
    for (int k4 = 0; k4 < 32; ++k4) {
        const float4 av[4] = {
            *(const float4*)&A[ty +  0][k4*4], *(const float4*)&A[ty + 16][k4*4],
            *(const float4*)&A[ty + 32][k4*4], *(const float4*)&A[ty + 48][k4*4]};
        const float4 bv[4] = {
            *(const float4*)&Bt[tx +  0][k4*4], *(const float4*)&Bt[tx + 16][k4*4],
            *(const float4*)&Bt[tx + 32][k4*4], *(const float4*)&Bt[tx + 48][k4*4]};
        #pragma unroll
        for (int i = 0; i < 4; ++i)
            #pragma unroll
            for (int u = 0; u < 4; ++u) {
                acc[i][u] = fmaf(av[i].x, bv[u].x, acc[i][u]);
                acc[i][u] = fmaf(av[i].y, bv[u].y, acc[i][u]);
                acc[i][u] = fmaf(av[i].z, bv[u].z, acc[i][u]);
                acc[i][u] = fmaf(av[i].w, bv[u].w, acc[i][u]);
            }
    }

    float bias[4];
    #pragma unroll
    for (int u = 0; u < 4; ++u) bias[u] = b_ih[col0 + tx + 16*u];
    #pragma unroll
    for (int i = 0; i < 4; ++i) {
        const size_t rowoff = (size_t)(row0 + ty + 16*i) * G3;
        #pragma unroll
        for (int u = 0; u < 4; ++u)
            xg[rowoff + col0 + tx + 16*u] = acc[i][u] + bias[u];
    }
}

// ---------------------------------------------------------------------------
// Kernel 3: sequential GRU. 256 blocks x 256 threads.
// Thread (j2, q) holds 6 weight slices of 32 floats = 192 VGPRs, PINNED via
// opaque asm so the compiler cannot sink the loads into the step loop.
// ---------------------------------------------------------------------------
__global__ __launch_bounds__(256, 1) void gru_kernel(
    const int*   __restrict__ lengths,
    const float* __restrict__ W_hh,
    const float* __restrict__ b_hh,
    const float* __restrict__ h0,
    const float* __restrict__ xg,
    float* __restrict__ out_dyn,
    float* __restrict__ out_h)
{
    __shared__ float hs[En];
    __shared__ float red[4][3][En];   // [q][gate][j]

    const int tid = threadIdx.x;
    const int b   = blockIdx.x;
    const int q   = tid >> 6;     // wave-uniform
    const int j2  = tid & 63;

    // slice s = a*3+g: rows g*128 + j2 + 64a, cols q*32..q*32+31
    float w[192];
    #pragma unroll
    for (int a = 0; a < 2; ++a)
        #pragma unroll
        for (int g = 0; g < 3; ++g) {
            const float4* p = (const float4*)(W_hh + (size_t)(g*En + j2 + 64*a) * En + q * 32);
            #pragma unroll
            for (int c = 0; c < 8; ++c)
                *(float4*)&w[((a*3+g)*8 + c)*4] = p[c];
        }
    #pragma unroll
    for (int i = 0; i < 192; ++i) asm volatile("" : "+v"(w[i]));

    const int len = lengths[b];
    const float* xgb = xg + (size_t)b * Tn * G3;
    float* outb = out_dyn + (size_t)b * Tn * En;

    float xr = 0.f, xz = 0.f, xn = 0.f, br = 0.f, bz = 0.f, bn = 0.f;
    if (tid < En) {
        hs[tid] = h0[(size_t)b * En + tid];
        br = b_hh[tid]; bz = b_hh[En + tid]; bn = b_hh[2*En + tid];
        xr = xgb[tid];  xz = xgb[En + tid]; xn = xgb[2*En + tid];
    }
    __syncthreads();

    for (int t = 0; t < len; ++t) {
        const float4* h4 = ((const float4*)hs) + q * 8;
        float acc[6] = {0.f, 0.f, 0.f, 0.f, 0.f, 0.f};
        #pragma unroll
        for (int c = 0; c < 8; ++c) {
            const float4 hv = h4[c];
            #pragma unroll
            for (int s = 0; s < 6; ++s) {
                acc[s] = fmaf(w[(s*8+c)*4+0], hv.x, acc[s]);
                acc[s] = fmaf(w[(s*8+c)*4+1], hv.y, acc[s]);
                acc[s] = fmaf(w[(s*8+c)*4+2], hv.z, acc[s]);
                acc[s] = fmaf(w[(s*8+c)*4+3], hv.w, acc[s]);
            }
        }
        // s = a*3+g
        red[q][0][j2]    = acc[0]; red[q][1][j2]    = acc[1]; red[q][2][j2]    = acc[2];
        red[q][0][j2+64] = acc[3]; red[q][1][j2+64] = acc[4]; red[q][2][j2+64] = acc[5];

        float nxr = 0.f, nxz = 0.f, nxn = 0.f;
        if (tid < En) {
            const int tn = (t + 1 < len) ? t + 1 : t;
            nxr = xgb[tn*G3 + tid];
            nxz = xgb[tn*G3 + En + tid];
            nxn = xgb[tn*G3 + 2*En + tid];
        }
        __syncthreads();

        if (tid < En) {
            const float ar = red[0][0][tid]+red[1][0][tid]+red[2][0][tid]+red[3][0][tid];
            const float az = red[0][1][tid]+red[1][1][tid]+red[2][1][tid]+red[3][1][tid];
            const float an = red[0][2][tid]+red[1][2][tid]+red[2][2][tid]+red[3][2][tid];
            const float r = sigmoidf(xr + br + ar);
            const float z = sigmoidf(xz + bz + az);
            const float n = tanh_safe(xn + r * (bn + an));
            const float hnew = (1.0f - z) * n + z * hs[tid];
            hs[tid] = hnew;
            outb[t*En + tid] = hnew;
            xr = nxr; xz = nxz; xn = nxn;
        }
        __syncthreads();
    }

    if (tid < En) {
        for (int t = len; t < Tn; ++t) outb[t*En + tid] = 0.0f;
        out_h[(size_t)b * En + tid] = hs[tid];
    }
}

extern "C" void kernel_launch(void* const* d_in, const int* in_sizes, int n_in,
                              void* d_out, int out_size, void* d_ws, size_t ws_size,
                              hipStream_t stream) {
    const int*   item_ids     = (const int*)d_in[0];
    const int*   basket_sizes = (const int*)d_in[1];
    const int*   lengths      = (const int*)d_in[2];
    const float* emb          = (const float*)d_in[3];
    const float* W_ih         = (const float*)d_in[4];
    const float* W_hh         = (const float*)d_in[5];
    const float* b_ih         = (const float*)d_in[6];
    const float* b_hh         = (const float*)d_in[7];
    const float* h0           = (const float*)d_in[8];
    float* out = (float*)d_out;
    float* xg  = (float*)d_ws;   // 19.7 MB
    float* ub  = out;            // reuse out_dyn region; overwritten by gru later

    gather_kernel<<<(Bn * Tn) / 8, 256, 0, stream>>>(item_ids, basket_sizes, emb, ub);
    gemm_kernel<<<1200, 256, 0, stream>>>(ub, W_ih, b_ih, xg);
    gru_kernel<<<Bn, 256, 0, stream>>>(
        lengths, W_hh, b_hh, h0, xg, out, out + (size_t)Bn * Tn * En);
}

// Round 6
// 180.523 us; speedup vs baseline: 1.0505x; 1.0505x over previous
//
#include <hip/hip_runtime.h>
#include <stdint.h>

#define Bn 256
#define Tn 50
#define Mn 20
#define En 128
#define G3 384
#define MT 64
#define LDA 132

__device__ __forceinline__ float sigmoidf(float x) {
    return 1.0f / (1.0f + __expf(-x));
}
__device__ __forceinline__ float tanh_safe(float a) {
    float ax = fabsf(a);
    float e2 = __expf(-2.0f * ax);
    return copysignf((1.0f - e2) / (1.0f + e2), a);
}

// ---------------------------------------------------------------------------
// Kernel 1: basket-mean gather -> ub [B*T][128]  (stored in d_out region)
// ---------------------------------------------------------------------------
__global__ __launch_bounds__(256) void gather_kernel(
    const int*   __restrict__ item_ids,
    const int*   __restrict__ basket_sizes,
    const float* __restrict__ emb,
    float* __restrict__ ub)
{
    const int bt   = blockIdx.x * 8 + (threadIdx.x >> 5);
    const int lane = threadIdx.x & 31;
    const int* ids = item_ids + (size_t)bt * Mn;
    float ax = 0.f, ay = 0.f, az = 0.f, aw = 0.f;
    #pragma unroll
    for (int m = 0; m < Mn; ++m) {
        const float4 v = *(const float4*)(emb + (size_t)ids[m] * En + lane * 4);
        ax += v.x; ay += v.y; az += v.z; aw += v.w;
    }
    const float inv = 1.0f / (float)basket_sizes[bt];
    *(float4*)(ub + (size_t)bt * En + lane * 4) =
        make_float4(ax * inv, ay * inv, az * inv, aw * inv);
}

// ---------------------------------------------------------------------------
// Kernel 2: xg = ub @ W_ih^T + b_ih.  1200 blocks (200 M x 6 N); 4x4 tile.
// ---------------------------------------------------------------------------
__global__ __launch_bounds__(256, 2) void gemm_kernel(
    const float* __restrict__ ub,
    const float* __restrict__ W_ih,
    const float* __restrict__ b_ih,
    float* __restrict__ xg)
{
    __shared__ float A[MT][LDA];
    __shared__ float Bt[64][LDA];

    const int tid  = threadIdx.x;
    const int mt   = blockIdx.x / 6;
    const int nc   = blockIdx.x % 6;
    const int row0 = mt * MT;
    const int col0 = nc * 64;

    {
        const int r = tid >> 2, seg = tid & 3;
        const float4* srcA = (const float4*)(ub + (size_t)(row0 + r) * En + seg * 32);
        const float4* srcB = (const float4*)(W_ih + (size_t)(col0 + r) * En + seg * 32);
        float4* dstA = (float4*)&A[r][seg * 32];
        float4* dstB = (float4*)&Bt[r][seg * 32];
        #pragma unroll
        for (int c = 0; c < 8; ++c) { dstA[c] = srcA[c]; dstB[c] = srcB[c]; }
    }
    __syncthreads();

    const int tx = tid & 15;
    const int ty = tid >> 4;

    float acc[4][4];
    #pragma unroll
    for (int i = 0; i < 4; ++i)
        #pragma unroll
        for (int u = 0; u < 4; ++u) acc[i][u] = 0.0f;

    #pragma unroll 4
    for (int k4 = 0; k4 < 32; ++k4) {
        const float4 av[4] = {
            *(const float4*)&A[ty +  0][k4*4], *(const float4*)&A[ty + 16][k4*4],
            *(const float4*)&A[ty + 32][k4*4], *(const float4*)&A[ty + 48][k4*4]};
        const float4 bv[4] = {
            *(const float4*)&Bt[tx +  0][k4*4], *(const float4*)&Bt[tx + 16][k4*4],
            *(const float4*)&Bt[tx + 32][k4*4], *(const float4*)&Bt[tx + 48][k4*4]};
        #pragma unroll
        for (int i = 0; i < 4; ++i)
            #pragma unroll
            for (int u = 0; u < 4; ++u) {
                acc[i][u] = fmaf(av[i].x, bv[u].x, acc[i][u]);
                acc[i][u] = fmaf(av[i].y, bv[u].y, acc[i][u]);
                acc[i][u] = fmaf(av[i].z, bv[u].z, acc[i][u]);
                acc[i][u] = fmaf(av[i].w, bv[u].w, acc[i][u]);
            }
    }

    float bias[4];
    #pragma unroll
    for (int u = 0; u < 4; ++u) bias[u] = b_ih[col0 + tx + 16*u];
    #pragma unroll
    for (int i = 0; i < 4; ++i) {
        const size_t rowoff = (size_t)(row0 + ty + 16*i) * G3;
        #pragma unroll
        for (int u = 0; u < 4; ++u)
            xg[rowoff + col0 + tx + 16*u] = acc[i][u] + bias[u];
    }
}

// ---------------------------------------------------------------------------
// Kernel 3: sequential GRU. 256 blocks x 512 threads.
// Thread (j in [0,128), q in [0,4)) holds 3 gate-row slices of 32 cols each =
// 96 weight floats. amdgpu_waves_per_eu(2,2) caps occupancy at 8 waves/CU so
// the allocator has a 256-VGPR budget -> weights stay register-resident.
// ---------------------------------------------------------------------------
__global__ __launch_bounds__(512)
__attribute__((amdgpu_waves_per_eu(2, 2)))
void gru_kernel(
    const int*   __restrict__ lengths,
    const float* __restrict__ W_hh,
    const float* __restrict__ b_hh,
    const float* __restrict__ h0,
    const float* __restrict__ xg,
    float* __restrict__ out_dyn,
    float* __restrict__ out_h)
{
    __shared__ float hs[En];
    __shared__ float red[12][En];     // [q*3+g][j]

    const int tid = threadIdx.x;
    const int b   = blockIdx.x;
    const int j   = tid & 127;
    const int q   = tid >> 7;         // wave-uniform (waves 0-1:q=0, ... 6-7:q=3)

    // weights: gate g row g*128+j, cols [q*32, q*32+32)
    float w[96];
    #pragma unroll
    for (int g = 0; g < 3; ++g) {
        const float4* p = (const float4*)(W_hh + (size_t)(g * En + j) * En + q * 32);
        #pragma unroll
        for (int c = 0; c < 8; ++c)
            *(float4*)&w[(g * 8 + c) * 4] = p[c];
    }
    #pragma unroll
    for (int i = 0; i < 96; ++i) asm volatile("" : "+v"(w[i]));

    const int len = lengths[b];
    const float* xgb = xg + (size_t)b * Tn * G3;
    float* outb = out_dyn + (size_t)b * Tn * En;

    float xr = 0.f, xz = 0.f, xn = 0.f, br = 0.f, bz = 0.f, bn = 0.f;
    if (tid < En) {
        hs[tid] = h0[(size_t)b * En + tid];
        br = b_hh[tid]; bz = b_hh[En + tid]; bn = b_hh[2*En + tid];
        xr = xgb[tid];  xz = xgb[En + tid]; xn = xgb[2*En + tid];
    }
    __syncthreads();

    for (int t = 0; t < len; ++t) {
        // phase A: partial dots over this thread's 32-col K-slice
        const float4* h4 = ((const float4*)hs) + q * 8;
        float a0 = 0.f, a1 = 0.f, a2 = 0.f;
        #pragma unroll
        for (int c = 0; c < 8; ++c) {
            const float4 hv = h4[c];
            a0 = fmaf(w[(0*8+c)*4+0], hv.x, a0); a0 = fmaf(w[(0*8+c)*4+1], hv.y, a0);
            a0 = fmaf(w[(0*8+c)*4+2], hv.z, a0); a0 = fmaf(w[(0*8+c)*4+3], hv.w, a0);
            a1 = fmaf(w[(1*8+c)*4+0], hv.x, a1); a1 = fmaf(w[(1*8+c)*4+1], hv.y, a1);
            a1 = fmaf(w[(1*8+c)*4+2], hv.z, a1); a1 = fmaf(w[(1*8+c)*4+3], hv.w, a1);
            a2 = fmaf(w[(2*8+c)*4+0], hv.x, a2); a2 = fmaf(w[(2*8+c)*4+1], hv.y, a2);
            a2 = fmaf(w[(2*8+c)*4+2], hv.z, a2); a2 = fmaf(w[(2*8+c)*4+3], hv.w, a2);
        }
        red[q*3+0][j] = a0; red[q*3+1][j] = a1; red[q*3+2][j] = a2;

        // prefetch next step's xg (overlaps barrier + phase B)
        float nxr = 0.f, nxz = 0.f, nxn = 0.f;
        if (tid < En) {
            const int tn = (t + 1 < len) ? t + 1 : t;
            nxr = xgb[tn*G3 + tid];
            nxz = xgb[tn*G3 + En + tid];
            nxn = xgb[tn*G3 + 2*En + tid];
        }
        __syncthreads();

        // phase B: reduce K-partials + gates (first 2 waves)
        if (tid < En) {
            const float ar = red[0][tid] + red[3][tid] + red[6][tid] + red[9][tid];
            const float az = red[1][tid] + red[4][tid] + red[7][tid] + red[10][tid];
            const float an = red[2][tid] + red[5][tid] + red[8][tid] + red[11][tid];
            const float r = sigmoidf(xr + br + ar);
            const float z = sigmoidf(xz + bz + az);
            const float n = tanh_safe(xn + r * (bn + an));
            const float hnew = (1.0f - z) * n + z * hs[tid];
            hs[tid] = hnew;
            outb[t*En + tid] = hnew;
            xr = nxr; xz = nxz; xn = nxn;
        }
        __syncthreads();
    }

    if (tid < En) {
        for (int t = len; t < Tn; ++t) outb[t*En + tid] = 0.0f;
        out_h[(size_t)b * En + tid] = hs[tid];
    }
}

extern "C" void kernel_launch(void* const* d_in, const int* in_sizes, int n_in,
                              void* d_out, int out_size, void* d_ws, size_t ws_size,
                              hipStream_t stream) {
    const int*   item_ids     = (const int*)d_in[0];
    const int*   basket_sizes = (const int*)d_in[1];
    const int*   lengths      = (const int*)d_in[2];
    const float* emb          = (const float*)d_in[3];
    const float* W_ih         = (const float*)d_in[4];
    const float* W_hh         = (const float*)d_in[5];
    const float* b_ih         = (const float*)d_in[6];
    const float* b_hh         = (const float*)d_in[7];
    const float* h0           = (const float*)d_in[8];
    float* out = (float*)d_out;
    float* xg  = (float*)d_ws;   // 19.7 MB
    float* ub  = out;            // reuse out_dyn region; overwritten by gru later

    gather_kernel<<<(Bn * Tn) / 8, 256, 0, stream>>>(item_ids, basket_sizes, emb, ub);
    gemm_kernel<<<1200, 256, 0, stream>>>(ub, W_ih, b_ih, xg);
    gru_kernel<<<Bn, 512, 0, stream>>>(
        lengths, W_hh, b_hh, h0, xg, out, out + (size_t)Bn * Tn * En);
}

// Round 7
// 176.506 us; speedup vs baseline: 1.0745x; 1.0228x over previous
//
#include <hip/hip_runtime.h>
#include <stdint.h>

#define Bn 256
#define Tn 50
#define Mn 20
#define En 128
#define G3 384
#define MT 64
#define LDA 132

__device__ __forceinline__ float sigmoidf(float x) {
    return 1.0f / (1.0f + __expf(-x));
}
__device__ __forceinline__ float tanh_safe(float a) {
    float ax = fabsf(a);
    float e2 = __expf(-2.0f * ax);
    return copysignf((1.0f - e2) / (1.0f + e2), a);
}

// ---------------------------------------------------------------------------
// Kernel 1: basket-mean gather -> ub [B*T][128]  (stored in d_out region)
// ---------------------------------------------------------------------------
__global__ __launch_bounds__(256) void gather_kernel(
    const int*   __restrict__ item_ids,
    const int*   __restrict__ basket_sizes,
    const float* __restrict__ emb,
    float* __restrict__ ub)
{
    const int bt   = blockIdx.x * 8 + (threadIdx.x >> 5);
    const int lane = threadIdx.x & 31;
    const int* ids = item_ids + (size_t)bt * Mn;
    float ax = 0.f, ay = 0.f, az = 0.f, aw = 0.f;
    #pragma unroll
    for (int m = 0; m < Mn; ++m) {
        const float4 v = *(const float4*)(emb + (size_t)ids[m] * En + lane * 4);
        ax += v.x; ay += v.y; az += v.z; aw += v.w;
    }
    const float inv = 1.0f / (float)basket_sizes[bt];
    *(float4*)(ub + (size_t)bt * En + lane * 4) =
        make_float4(ax * inv, ay * inv, az * inv, aw * inv);
}

// ---------------------------------------------------------------------------
// Kernel 2: xg = ub @ W_ih^T + b_ih.  1200 blocks (200 M x 6 N); 4x4 tile.
// ---------------------------------------------------------------------------
__global__ __launch_bounds__(256, 2) void gemm_kernel(
    const float* __restrict__ ub,
    const float* __restrict__ W_ih,
    const float* __restrict__ b_ih,
    float* __restrict__ xg)
{
    __shared__ float A[MT][LDA];
    __shared__ float Bt[64][LDA];

    const int tid  = threadIdx.x;
    const int mt   = blockIdx.x / 6;
    const int nc   = blockIdx.x % 6;
    const int row0 = mt * MT;
    const int col0 = nc * 64;

    {
        const int r = tid >> 2, seg = tid & 3;
        const float4* srcA = (const float4*)(ub + (size_t)(row0 + r) * En + seg * 32);
        const float4* srcB = (const float4*)(W_ih + (size_t)(col0 + r) * En + seg * 32);
        float4* dstA = (float4*)&A[r][seg * 32];
        float4* dstB = (float4*)&Bt[r][seg * 32];
        #pragma unroll
        for (int c = 0; c < 8; ++c) { dstA[c] = srcA[c]; dstB[c] = srcB[c]; }
    }
    __syncthreads();

    const int tx = tid & 15;
    const int ty = tid >> 4;

    float acc[4][4];
    #pragma unroll
    for (int i = 0; i < 4; ++i)
        #pragma unroll
        for (int u = 0; u < 4; ++u) acc[i][u] = 0.0f;

    #pragma unroll 4
    for (int k4 = 0; k4 < 32; ++k4) {
        const float4 av[4] = {
            *(const float4*)&A[ty +  0][k4*4], *(const float4*)&A[ty + 16][k4*4],
            *(const float4*)&A[ty + 32][k4*4], *(const float4*)&A[ty + 48][k4*4]};
        const float4 bv[4] = {
            *(const float4*)&Bt[tx +  0][k4*4], *(const float4*)&Bt[tx + 16][k4*4],
            *(const float4*)&Bt[tx + 32][k4*4], *(const float4*)&Bt[tx + 48][k4*4]};
        #pragma unroll
        for (int i = 0; i < 4; ++i)
            #pragma unroll
            for (int u = 0; u < 4; ++u) {
                acc[i][u] = fmaf(av[i].x, bv[u].x, acc[i][u]);
                acc[i][u] = fmaf(av[i].y, bv[u].y, acc[i][u]);
                acc[i][u] = fmaf(av[i].z, bv[u].z, acc[i][u]);
                acc[i][u] = fmaf(av[i].w, bv[u].w, acc[i][u]);
            }
    }

    float bias[4];
    #pragma unroll
    for (int u = 0; u < 4; ++u) bias[u] = b_ih[col0 + tx + 16*u];
    #pragma unroll
    for (int i = 0; i < 4; ++i) {
        const size_t rowoff = (size_t)(row0 + ty + 16*i) * G3;
        #pragma unroll
        for (int u = 0; u < 4; ++u)
            xg[rowoff + col0 + tx + 16*u] = acc[i][u] + bias[u];
    }
}

// ---------------------------------------------------------------------------
// Kernel 3: sequential GRU. 256 blocks x 1024 threads.
// Thread (j in [0,128), q in [0,8)) holds 3 gate-row slices of 16 cols each =
// 48 weight floats in SROA-friendly float4[4] arrays (constant indices only,
// never address-taken) -> ~95 VGPRs, under the 128 budget at 4 waves/EU, so
// the compiler keeps them live across the step loop.
// ---------------------------------------------------------------------------
__global__ __launch_bounds__(1024) void gru_kernel(
    const int*   __restrict__ lengths,
    const float* __restrict__ W_hh,
    const float* __restrict__ b_hh,
    const float* __restrict__ h0,
    const float* __restrict__ xg,
    float* __restrict__ out_dyn,
    float* __restrict__ out_h)
{
    __shared__ float hs[En];
    __shared__ float red[8][3][En];   // [q][gate][j], 12 KB

    const int tid = threadIdx.x;
    const int b   = blockIdx.x;
    const int j   = tid & 127;
    const int q   = tid >> 7;         // [0,8), wave-uniform

    // gate g row g*128+j, cols [q*16, q*16+16)
    float4 w0[4], w1[4], w2[4];
    {
        const float4* p0 = (const float4*)(W_hh + (size_t)(0*En + j) * En + q * 16);
        const float4* p1 = (const float4*)(W_hh + (size_t)(1*En + j) * En + q * 16);
        const float4* p2 = (const float4*)(W_hh + (size_t)(2*En + j) * En + q * 16);
        #pragma unroll
        for (int c = 0; c < 4; ++c) { w0[c] = p0[c]; w1[c] = p1[c]; w2[c] = p2[c]; }
    }

    const int len = lengths[b];
    const float* xgb = xg + (size_t)b * Tn * G3;
    float* outb = out_dyn + (size_t)b * Tn * En;

    float xr = 0.f, xz = 0.f, xn = 0.f, br = 0.f, bz = 0.f, bn = 0.f;
    if (tid < En) {
        hs[tid] = h0[(size_t)b * En + tid];
        br = b_hh[tid]; bz = b_hh[En + tid]; bn = b_hh[2*En + tid];
        xr = xgb[tid];  xz = xgb[En + tid]; xn = xgb[2*En + tid];
    }
    __syncthreads();

    for (int t = 0; t < len; ++t) {
        // phase A: partial dots over this thread's 16-col K-slice (broadcast LDS)
        const float4* h4 = ((const float4*)hs) + q * 4;
        float a0 = 0.f, a1 = 0.f, a2 = 0.f;
        #pragma unroll
        for (int c = 0; c < 4; ++c) {
            const float4 hv = h4[c];
            a0 = fmaf(w0[c].x, hv.x, a0); a0 = fmaf(w0[c].y, hv.y, a0);
            a0 = fmaf(w0[c].z, hv.z, a0); a0 = fmaf(w0[c].w, hv.w, a0);
            a1 = fmaf(w1[c].x, hv.x, a1); a1 = fmaf(w1[c].y, hv.y, a1);
            a1 = fmaf(w1[c].z, hv.z, a1); a1 = fmaf(w1[c].w, hv.w, a1);
            a2 = fmaf(w2[c].x, hv.x, a2); a2 = fmaf(w2[c].y, hv.y, a2);
            a2 = fmaf(w2[c].z, hv.z, a2); a2 = fmaf(w2[c].w, hv.w, a2);
        }
        red[q][0][j] = a0; red[q][1][j] = a1; red[q][2][j] = a2;

        // prefetch next step's xg (overlaps barrier + phase B)
        float nxr = 0.f, nxz = 0.f, nxn = 0.f;
        if (tid < En) {
            const int tn = (t + 1 < len) ? t + 1 : t;
            nxr = xgb[tn*G3 + tid];
            nxz = xgb[tn*G3 + En + tid];
            nxn = xgb[tn*G3 + 2*En + tid];
        }
        __syncthreads();

        // phase B: reduce K-partials + gates (first 2 waves)
        if (tid < En) {
            float ar = red[0][0][tid], az = red[0][1][tid], an = red[0][2][tid];
            #pragma unroll
            for (int p = 1; p < 8; ++p) {
                ar += red[p][0][tid]; az += red[p][1][tid]; an += red[p][2][tid];
            }
            const float r = sigmoidf(xr + br + ar);
            const float z = sigmoidf(xz + bz + az);
            const float n = tanh_safe(xn + r * (bn + an));
            const float hnew = (1.0f - z) * n + z * hs[tid];
            hs[tid] = hnew;
            outb[t*En + tid] = hnew;
            xr = nxr; xz = nxz; xn = nxn;
        }
        __syncthreads();
    }

    if (tid < En) {
        for (int t = len; t < Tn; ++t) outb[t*En + tid] = 0.0f;
        out_h[(size_t)b * En + tid] = hs[tid];
    }
}

extern "C" void kernel_launch(void* const* d_in, const int* in_sizes, int n_in,
                              void* d_out, int out_size, void* d_ws, size_t ws_size,
                              hipStream_t stream) {
    const int*   item_ids     = (const int*)d_in[0];
    const int*   basket_sizes = (const int*)d_in[1];
    const int*   lengths      = (const int*)d_in[2];
    const float* emb          = (const float*)d_in[3];
    const float* W_ih         = (const float*)d_in[4];
    const float* W_hh         = (const float*)d_in[5];
    const float* b_ih         = (const float*)d_in[6];
    const float* b_hh         = (const float*)d_in[7];
    const float* h0           = (const float*)d_in[8];
    float* out = (float*)d_out;
    float* xg  = (float*)d_ws;   // 19.7 MB
    float* ub  = out;            // reuse out_dyn region; overwritten by gru later

    gather_kernel<<<(Bn * Tn) / 8, 256, 0, stream>>>(item_ids, basket_sizes, emb, ub);
    gemm_kernel<<<1200, 256, 0, stream>>>(ub, W_ih, b_ih, xg);
    gru_kernel<<<Bn, 1024, 0, stream>>>(
        lengths, W_hh, b_hh, h0, xg, out, out + (size_t)Bn * Tn * En);
}